// Round 8
// baseline (40.590 us; speedup 1.0000x reference)
//
#include <hip/hip_runtime.h>
#include <math.h>

#define CCH     128
#define HWTOK   4096
#define MROWS   512
#define THREADS 1024   // 16 waves per block; 256 blocks = 1 block per CU

using short8  = __attribute__((ext_vector_type(8))) short;
using float16 = __attribute__((ext_vector_type(16))) float;
using f4      = __attribute__((ext_vector_type(4))) float;
using i4      = __attribute__((ext_vector_type(4))) int;

__device__ __forceinline__ unsigned f2bf_rne(float f) {
    unsigned u = __builtin_bit_cast(unsigned, f);
    return (u + 0x7FFFu + ((u >> 16) & 1u)) >> 16;
}
__device__ __forceinline__ float fmax3(float a, float b, float c) {
    return fmaxf(fmaxf(a, b), c);   // clang fuses to v_max3_f32
}

// ---------------------------------------------------------------------------
// Prep: pre-normalized bf16 memory rows as MFMA A-fragments in ws.
// fid = (mt*8 + kstep)*64 + lane, lane = hi*32 + r5:
//   holds memory[mt*32 + r5][kstep*16 + hi*8 + j] * rinv(row), j = 0..7 (bf16)
// ---------------------------------------------------------------------------
__global__ __launch_bounds__(256) void frag_kernel(const float* __restrict__ mem,
                                                   i4* __restrict__ wsfrag) {
    int fid   = blockIdx.x * 256 + threadIdx.x;   // 0..8191
    int mt    = fid >> 9;
    int rem   = fid & 511;
    int kstep = rem >> 6;
    int l     = rem & 63;
    int hi    = l >> 5, r5 = l & 31;
    int row   = mt * 32 + r5;
    int k0    = kstep * 16 + hi * 8;

    const float* mr = mem + (size_t)row * CCH;
    float s = 0.f;
    #pragma unroll
    for (int c = 0; c < CCH; c += 4) {
        f4 v = *reinterpret_cast<const f4*>(mr + c);
        s += v.x * v.x + v.y * v.y + v.z * v.z + v.w * v.w;
    }
    float sc = 1.0f / fmaxf(sqrtf(s), 1e-12f);

    unsigned p[4];
    #pragma unroll
    for (int j = 0; j < 4; ++j) {
        unsigned lo   = f2bf_rne(mr[k0 + 2 * j]     * sc);
        unsigned hi16 = f2bf_rne(mr[k0 + 2 * j + 1] * sc);
        p[j] = lo | (hi16 << 16);
    }
    i4 o; o.x = p[0]; o.y = p[1]; o.z = p[2]; o.w = p[3];
    wsfrag[fid] = o;
}

// ---------------------------------------------------------------------------
// Main: 256 blocks x 16 waves (1024 thr). Whole 128 KB fragment table staged
// in LDS once per block. KEY CHANGE vs r7: the x-fragment build (the bulk of
// HBM reads) moved AFTER the barrier, so post-barrier every wave is an
// independent {x-load -> MFMA -> store} pipeline — early waves' stores
// overlap late waves' loads (r7 serialized the whole block on the slowest
// x-load via the barrier's vmcnt(0) drain, then stored in lockstep).
// ---------------------------------------------------------------------------
__global__ __launch_bounds__(THREADS, 4) void hardmem_mfma(
    const float* __restrict__ x, const float* __restrict__ mem,
    const i4* __restrict__ wsfrag, float* __restrict__ out)
{
    __shared__ i4 sfrag[8192];   // 128 KB — whole fragment table

    const int tid  = threadIdx.x;
    const int wid  = tid >> 6;                 // 0..15
    const int lane = tid & 63;
    const int l5   = lane & 31, hi = lane >> 5;

    const int b   = blockIdx.x >> 3;                     // 8 blocks/batch
    const int tb0 = (blockIdx.x & 7) * 512 + wid * 32;   // wave token base
    const float* xb = x + (size_t)b * CCH * HWTOK;

    // ---- stage fragment table -> LDS (L2-hot: 128 KB shared by all blocks)
    #pragma unroll
    for (int i = 0; i < 8; ++i) {
        int idx = tid + i * THREADS;           // 0..8191
        sfrag[idx] = wsfrag[idx];
    }
    __syncthreads();   // orders sfrag writes vs reads; everything below is
                       // wave-independent (no further block-wide syncs)

    // ---- build x B-fragment (token = tb0+l5); fp32 sum-of-squares on the fly
    short8 bf[8];
    float  s2;
    {
        const float* xt = xb + tb0 + l5;
        float s = 0.f;
        #pragma unroll
        for (int kstep = 0; kstep < 8; ++kstep) {
            const int c0 = kstep * 16 + hi * 8;
            float v[8];
            #pragma unroll
            for (int j = 0; j < 8; ++j) v[j] = xt[(size_t)(c0 + j) * HWTOK];
            unsigned p[4];
            #pragma unroll
            for (int j = 0; j < 4; ++j) {
                s = fmaf(v[2 * j],     v[2 * j],     s);
                s = fmaf(v[2 * j + 1], v[2 * j + 1], s);
                unsigned u0 = __builtin_bit_cast(unsigned, v[2 * j]);
                unsigned u1 = __builtin_bit_cast(unsigned, v[2 * j + 1]);
                p[j] = (u0 >> 16) | (u1 & 0xFFFF0000u);   // truncate-to-bf16
            }
            i4 pk; pk.x = p[0]; pk.y = p[1]; pk.z = p[2]; pk.w = p[3];
            bf[kstep] = __builtin_bit_cast(short8, pk);
        }
        s2 = s;
    }

    // ---- hot loop: max-only over 512 rows, A-frags from LDS
    float bmax = -1e30f;
    for (int mt = 0; mt < 16; ++mt) {
        short8 af[8];
        #pragma unroll
        for (int k = 0; k < 8; ++k)
            af[k] = __builtin_bit_cast(short8, sfrag[(mt * 8 + k) * 64 + lane]);

        float16 acc;
        #pragma unroll
        for (int r = 0; r < 16; ++r) acc[r] = 0.f;
        #pragma unroll
        for (int k = 0; k < 8; ++k)
            acc = __builtin_amdgcn_mfma_f32_32x32x16_bf16(af[k], bf[k], acc, 0, 0, 0);

        float m0 = fmax3(acc[0], acc[1], acc[2]);
        float m1 = fmax3(acc[3], acc[4], acc[5]);
        float m2 = fmax3(acc[6], acc[7], acc[8]);
        float m3 = fmax3(acc[9], acc[10], acc[11]);
        float m4 = fmax3(acc[12], acc[13], acc[14]);
        bmax = fmaxf(bmax, fmax3(fmax3(m0, m1, m2), fmax3(m3, m4, acc[15]), bmax));
    }

    // ---- threshold: bv/||x|| > 0.8  <=>  bv > 0.8*||x|| (norm > 0)
    bmax = fmaxf(bmax, __shfl_xor(bmax, 32));
    const float n2  = s2 + __shfl_xor(s2, 32);
    const bool  msk = bmax > 0.8f * fmaxf(sqrtf(n2), 1e-12f);

    const unsigned long long wb = __ballot(msk);

    // wave-local epilogue: lane's token t = tb0 + (lane&31); per instruction
    // lanes 0..31 cover one full 128B line (32 tokens) at channel 2k,
    // lanes 32..63 the line at channel 2k+1.
    float* ob = out + (size_t)b * CCH * HWTOK;
    const int t     = tb0 + (lane & 31);
    const int chalf = lane >> 5;

    if (wb == 0ULL) {
        // ---- fast path: zero-fill this wave's 32 tokens x 128 channels
        #pragma unroll 8
        for (int k = 0; k < 64; ++k) {
            int c = chalf + 2 * k;
            ob[(size_t)c * HWTOK + t] = 0.f;
        }
    } else {
        // ---- rare path: exact argmax recompute (identical MFMAs), gather
        float bestv = -1e30f; int besti = 0;
        for (int mt = 0; mt < 16; ++mt) {
            short8 af[8];
            #pragma unroll
            for (int k = 0; k < 8; ++k)
                af[k] = __builtin_bit_cast(short8, sfrag[(mt * 8 + k) * 64 + lane]);
            float16 acc;
            #pragma unroll
            for (int r = 0; r < 16; ++r) acc[r] = 0.f;
            #pragma unroll
            for (int k = 0; k < 8; ++k)
                acc = __builtin_amdgcn_mfma_f32_32x32x16_bf16(af[k], bf[k], acc, 0, 0, 0);
            const int rbase = mt * 32 + 4 * hi;
            #pragma unroll
            for (int r = 0; r < 16; ++r) {
                // verified C/D map: row=(reg&3)+8*(reg>>2)+4*(lane>>5); ascending in r
                const int row = rbase + (r & 3) + 8 * (r >> 2);
                if (acc[r] > bestv) { bestv = acc[r]; besti = row; }
            }
        }
        float ov = __shfl_xor(bestv, 32);
        int   oi = __shfl_xor(besti, 32);
        if (ov > bestv || (ov == bestv && oi < besti)) { bestv = ov; besti = oi; }

        const float* mrow = mem + (size_t)besti * CCH;
        #pragma unroll 8
        for (int k = 0; k < 64; ++k) {
            int c = chalf + 2 * k;
            float val = msk ? mrow[c] : 0.f;
            ob[(size_t)c * HWTOK + t] = val;
        }
    }
}

// ---------------------------------------------------------------------------
extern "C" void kernel_launch(void* const* d_in, const int* in_sizes, int n_in,
                              void* d_out, int out_size, void* d_ws, size_t ws_size,
                              hipStream_t stream) {
    const float* x   = (const float*)d_in[0];   // [32,128,64,64]
    const float* mem = (const float*)d_in[1];   // [512,128]
    float* out       = (float*)d_out;
    i4* wsfrag       = (i4*)d_ws;               // 128 KB fragment workspace

    frag_kernel<<<32, 256, 0, stream>>>(mem, wsfrag);
    hardmem_mfma<<<256, THREADS, 0, stream>>>(x, mem, wsfrag, out);
}